// Round 1
// 324.710 us; speedup vs baseline: 1.0009x; 1.0009x over previous
//
#include <hip/hip_runtime.h>

// Unfold: x (B=16, C=128, H=64, W=64) f32 -> y (B, C*9, H*W) f32
// y[bc, t, h*W+w] = x[bc, h+dh, w+dw] (zero-padded), t = (dh+1)*3 + (dw+1)
//
// One block per (b,c) plane: read the 16 KB plane from HBM exactly once,
// stage into LDS with a zero halo, write 9 shifted copies coalesced.
// Traffic: 33.5 MB read + 302 MB written -> ~53 us floor at 6.3 TB/s.
//
// R1 change: drop __builtin_nontemporal_store -> plain stores. The harness's
// own fillBuffer sustains 6.35 TB/s with plain stores on this very buffer;
// nt (L2-bypass) is the prime suspect for the kernel's ~2.5 TB/s effective
// store rate (nt stores retire vmcnt at HBM, serializing the unrolled
// store chain on register-reuse waits).
//
// LDS: 66 rows x stride 67 (halo at row/col 0 and 65, col 66 pad). Stride 67
// puts the wave's four 16-lane row-groups on disjoint bank residues mod 4 ->
// only the free 2-way aliasing.
//
// Ordering: issue the 4 global loads first, zero the halo while they are in
// flight, then write the interior -> a single barrier instead of two.

#define S 67
#define LDS_ELEMS (66 * S)

typedef float f32x4 __attribute__((ext_vector_type(4)));

__global__ __launch_bounds__(256) void unfold_kernel(
    const float* __restrict__ x, float* __restrict__ y) {
    __shared__ float lds[LDS_ELEMS];
    const int j  = threadIdx.x;
    const int bc = blockIdx.x;

    // 1) Issue the plane loads (4 x 16 B per thread, coalesced) immediately.
    const f32x4* plane = (const f32x4*)(x + ((size_t)bc << 12));
    f32x4 v0 = plane[j];
    f32x4 v1 = plane[256 + j];
    f32x4 v2 = plane[512 + j];
    f32x4 v3 = plane[768 + j];

    // 2) Zero only the halo (262 elements) while the loads are in flight.
    if (j < S) {
        lds[j] = 0.f;                 // top halo row
        lds[65 * S + j] = 0.f;        // bottom halo row
    }
    if (j < 64) {
        lds[(j + 1) * S] = 0.f;       // left halo col
        lds[(j + 1) * S + 65] = 0.f;  // right halo col
    }

    // 3) Interior writes (h = f>>4, w = (f&15)*4 for f = q*256 + j).
    #pragma unroll
    for (int q = 0; q < 4; ++q) {
        f32x4 v = (q == 0) ? v0 : (q == 1) ? v1 : (q == 2) ? v2 : v3;
        int f = q * 256 + j;
        int h = f >> 4;
        int w = (f & 15) << 2;
        float* dst = &lds[(h + 1) * S + (w + 1)];
        dst[0] = v.x; dst[1] = v.y; dst[2] = v.z; dst[3] = v.w;
    }
    __syncthreads();

    // 4) Emit the 9 shifted copies; plain coalesced 16 B stores (through L2).
    float* ybase = y + ((size_t)bc * 9 << 12);
    #pragma unroll
    for (int t = 0; t < 9; ++t) {
        const int dh = t / 3 - 1;
        const int dw = t % 3 - 1;
        f32x4* yt = (f32x4*)(ybase + ((size_t)t << 12));
        #pragma unroll
        for (int q = 0; q < 4; ++q) {
            int f = q * 256 + j;
            int h = f >> 4;
            int w = (f & 15) << 2;
            const float* s = &lds[(h + 1 + dh) * S + (w + 1 + dw)];
            f32x4 v;
            v.x = s[0]; v.y = s[1]; v.z = s[2]; v.w = s[3];
            yt[f] = v;
        }
    }
}

extern "C" void kernel_launch(void* const* d_in, const int* in_sizes, int n_in,
                              void* d_out, int out_size, void* d_ws, size_t ws_size,
                              hipStream_t stream) {
    const float* x = (const float*)d_in[0];
    // d_in[1] is the fixed identity eye(9) kernel -- effect hard-coded.
    float* y = (float*)d_out;

    // B*C = 2048 planes -> 2048 blocks (8 per CU on 256 CUs = 32 waves/CU).
    unfold_kernel<<<2048, 256, 0, stream>>>(x, y);
}